// Round 1
// baseline (1452.802 us; speedup 1.0000x reference)
//
#include <hip/hip_runtime.h>

// SJLT projection: out[b, idx[d,j]] += x[b,d] * sgn[d,j]; out *= 1/sqrt(c)
// B=32, D=1e6, P=4096, c=8.
//
// Strategy: LDS-resident accumulators for BG=8 batch rows (128 KB static LDS,
// gfx950 allows 160 KB). Grid (64 d-chunks, 4 batch groups) = 256 blocks of
// 1024 threads -> 1 block/CU. Per d: vectorized int4 loads of idx/sgn,
// sign applied by XOR of sign bit, ds_add_f32 into LDS; final flush via
// native global_atomic_add_f32 (unsafeAtomicAdd).

#define D_TOTAL 1000000
#define PROJ    4096
#define C_SK    8
#define BG      8       // batch rows per block (LDS = BG*PROJ*4 = 128 KB)
#define NCHUNK  64      // d-chunks; 64*15625 = 1e6 exactly
#define BLOCK   1024

__global__ __launch_bounds__(BLOCK, 4)
void sjlt_scatter_kernel(const float* __restrict__ x,
                         const int*   __restrict__ idx,
                         const int*   __restrict__ sgn,
                         float* __restrict__ out)
{
    __shared__ float acc[BG * PROJ];

    const int tid = threadIdx.x;

    // zero the LDS accumulators (32 elems/thread)
    #pragma unroll
    for (int i = 0; i < (BG * PROJ) / BLOCK; ++i)
        acc[i * BLOCK + tid] = 0.0f;
    __syncthreads();

    const int chunk = D_TOTAL / NCHUNK;          // 15625
    const int d0 = blockIdx.x * chunk;
    const int d1 = d0 + chunk;                   // never exceeds D_TOTAL
    const int bg = blockIdx.y * BG;              // first batch row of this block

    for (int d = d0 + tid; d < d1; d += BLOCK) {
        // idx/sgn are [D][8] row-major: 32 B per d, 16B-aligned -> int4 x2
        const int4 i0 = *(const int4*)(idx + (size_t)d * C_SK);
        const int4 i1 = *(const int4*)(idx + (size_t)d * C_SK + 4);
        const int4 s0 = *(const int4*)(sgn + (size_t)d * C_SK);
        const int4 s1 = *(const int4*)(sgn + (size_t)d * C_SK + 4);

        #pragma unroll
        for (int b = 0; b < BG; ++b) {
            // nontemporal: x is streamed once; keep L3 for idx/sgn re-reads
            const float xv = __builtin_nontemporal_load(
                x + (size_t)(bg + b) * D_TOTAL + d);
            const unsigned xb = __float_as_uint(xv);
            float* accb = acc + b * PROJ;
            // sign in {-1,+1}: sign bit of the int32 is the flip bit
            atomicAdd(accb + i0.x, __uint_as_float(xb ^ ((unsigned)s0.x & 0x80000000u)));
            atomicAdd(accb + i0.y, __uint_as_float(xb ^ ((unsigned)s0.y & 0x80000000u)));
            atomicAdd(accb + i0.z, __uint_as_float(xb ^ ((unsigned)s0.z & 0x80000000u)));
            atomicAdd(accb + i0.w, __uint_as_float(xb ^ ((unsigned)s0.w & 0x80000000u)));
            atomicAdd(accb + i1.x, __uint_as_float(xb ^ ((unsigned)s1.x & 0x80000000u)));
            atomicAdd(accb + i1.y, __uint_as_float(xb ^ ((unsigned)s1.y & 0x80000000u)));
            atomicAdd(accb + i1.z, __uint_as_float(xb ^ ((unsigned)s1.z & 0x80000000u)));
            atomicAdd(accb + i1.w, __uint_as_float(xb ^ ((unsigned)s1.w & 0x80000000u)));
        }
    }
    __syncthreads();

    // flush: scale and atomically add into global out
    const float scale = 0.35355339059327373f;    // 1/sqrt(8)
    #pragma unroll
    for (int i = 0; i < (BG * PROJ) / BLOCK; ++i) {
        const int lin = i * BLOCK + tid;
        const int b = lin >> 12;                 // /PROJ
        const int p = lin & (PROJ - 1);
        unsafeAtomicAdd(out + (size_t)(bg + b) * PROJ + p, acc[lin] * scale);
    }
}

extern "C" void kernel_launch(void* const* d_in, const int* in_sizes, int n_in,
                              void* d_out, int out_size, void* d_ws, size_t ws_size,
                              hipStream_t stream) {
    const float* x   = (const float*)d_in[0];
    const int*   idx = (const int*)d_in[1];
    const int*   sgn = (const int*)d_in[2];
    float*       out = (float*)d_out;

    // d_out is poisoned before every timed launch -> zero it on-stream
    hipMemsetAsync(out, 0, (size_t)out_size * sizeof(float), stream);

    dim3 grid(NCHUNK, 32 / BG);
    sjlt_scatter_kernel<<<grid, BLOCK, 0, stream>>>(x, idx, sgn, out);
}

// Round 2
// 880.203 us; speedup vs baseline: 1.6505x; 1.6505x over previous
//
#include <hip/hip_runtime.h>
#include <hip/hip_fp16.h>

// SJLT projection: out[b, idx[d,j]] += x[b,d]*sgn[d,j]; out *= 1/sqrt(8)
// B=32, D=1e6, P=4096, c=8.
//
// R1 post-mortem: LDS atomic RMW measured at ~3.1 cyc/lane (198 cyc/wave-inst)
// -> 256M scatter atomics have a ~1.28 ms floor. Restructure as bucket-sort +
// register-accumulated gather:
//   K0: cursors[p] = p*CAP                    (CAP=2560 >> Poisson max ~2130)
//   K3: sort 8M (d,j,sign) entries by bucket via global fetch-add cursors
//   K4: transpose x -> x_T[1e6][32] fp16 (err sigma ~0.006 << 1.46 threshold)
//   K5: per bucket: walk list, each entry = one 64B x_T line, accumulate in
//       VGPRs, shfl-reduce, plain stores. Zero atomics in the hot phase.

#define D_TOTAL 1000000
#define PROJ    4096
#define C_SK    8
#define CAP     2560
#define SCALE   0.35355339059327373f

#define LIST_OFF   65536
#define LIST_BYTES (PROJ * CAP * 4)            // 41,943,040
#define XT_OFF     (LIST_OFF + LIST_BYTES)     // 42,008,576
#define XT_BYTES   (D_TOTAL * 32 * 2)          // 64,000,000 (fp16)
#define WS_NEEDED  ((size_t)XT_OFF + XT_BYTES) // ~106 MB

// ---------------- K0: init per-bucket cursors ----------------
__global__ void init_cursors_kernel(int* __restrict__ cursors) {
    int i = blockIdx.x * blockDim.x + threadIdx.x;
    if (i < PROJ) cursors[i] = i * CAP;
}

// ---------------- K3: bucket-sort the 8M entries ----------------
// payload bit31 = sign, bits 0..22 = g = d*8+j
__global__ __launch_bounds__(256, 8)
void scatter_sort_kernel(const int* __restrict__ idx,
                         const int* __restrict__ sgn,
                         int* __restrict__ cursors,
                         int* __restrict__ list) {
    const int gid = blockIdx.x * 256 + threadIdx.x;   // 2048*256 = 524288 threads
    const int NV = (D_TOTAL * C_SK) / 4;              // 2,000,000 int4s
    #pragma unroll
    for (int k = 0; k < 4; ++k) {
        int v = k * 524288 + gid;
        if (v < NV) {
            const int4 i4 = ((const int4*)idx)[v];
            const int4 s4 = ((const int4*)sgn)[v];
            const int g0 = v * 4;
            int pos;
            pos = atomicAdd(cursors + i4.x, 1);
            list[pos] = (g0 + 0) | ((unsigned)s4.x & 0x80000000u);
            pos = atomicAdd(cursors + i4.y, 1);
            list[pos] = (g0 + 1) | ((unsigned)s4.y & 0x80000000u);
            pos = atomicAdd(cursors + i4.z, 1);
            list[pos] = (g0 + 2) | ((unsigned)s4.z & 0x80000000u);
            pos = atomicAdd(cursors + i4.w, 1);
            list[pos] = (g0 + 3) | ((unsigned)s4.w & 0x80000000u);
        }
    }
}

// ---------------- K4: transpose x[32][1e6] -> x_T[1e6][32] fp16 ----------------
__global__ __launch_bounds__(1024)
void transpose_kernel(const float* __restrict__ x, unsigned short* __restrict__ xT) {
    __shared__ float tile[32][1025];                  // +1 pad: conflict-free
    const int tid = threadIdx.x;
    const int d0 = blockIdx.x * 1024;

    if (d0 + 1024 <= D_TOTAL) {
        #pragma unroll
        for (int rr = 0; rr < 8; ++rr) {
            const int r = rr * 4 + (tid >> 8);
            const int c = (tid & 255) * 4;
            const float4 v = *(const float4*)(x + (size_t)r * D_TOTAL + d0 + c);
            tile[r][c] = v.x; tile[r][c+1] = v.y; tile[r][c+2] = v.z; tile[r][c+3] = v.w;
        }
    } else {
        for (int rr = 0; rr < 8; ++rr) {
            const int r = rr * 4 + (tid >> 8);
            const int c = (tid & 255) * 4;
            for (int m = 0; m < 4; ++m) {
                const int d = d0 + c + m;
                tile[r][c + m] = (d < D_TOTAL) ? x[(size_t)r * D_TOTAL + d] : 0.f;
            }
        }
    }
    __syncthreads();

    #pragma unroll
    for (int k = 0; k < 8; ++k) {
        const int i  = k * 1024 + tid;
        const int dl = i >> 3;            // local d
        const int b0 = (i & 7) * 4;       // first of 4 batch rows
        if (d0 + dl < D_TOTAL) {
            ushort4 h;
            h.x = __half_as_ushort(__float2half(tile[b0    ][dl]));
            h.y = __half_as_ushort(__float2half(tile[b0 + 1][dl]));
            h.z = __half_as_ushort(__float2half(tile[b0 + 2][dl]));
            h.w = __half_as_ushort(__float2half(tile[b0 + 3][dl]));
            *(ushort4*)(xT + (size_t)d0 * 32 + (size_t)i * 4) = h;
        }
    }
}

// ---------------- K5: gather per bucket, register accumulation ----------------
// block = 256 thr = 4 waves = 2 buckets x 2 waves. Lane layout per wave:
// 8 entry-groups (g8 = lane>>3) x 8 b-quads (bsub = lane&7, b = bsub*4..+3).
__global__ __launch_bounds__(256, 8)
void gather_kernel(const int* __restrict__ cursors,
                   const int* __restrict__ list,
                   const unsigned short* __restrict__ xT,
                   float* __restrict__ out) {
    __shared__ float red[4][32];
    const int tid  = threadIdx.x;
    const int w    = tid >> 6;
    const int lane = tid & 63;
    const int p    = blockIdx.x * 2 + (w >> 1);
    const int half_ = w & 1;
    const int start = p * CAP;
    const int end   = cursors[p];                 // start + count after K3
    const int g8   = lane >> 3;
    const int bsub = lane & 7;

    float a0 = 0.f, a1 = 0.f, a2 = 0.f, a3 = 0.f;
    #pragma unroll 4
    for (int i0 = start + half_ * 8; i0 < end; i0 += 16) {
        const int  e  = i0 + g8;
        const bool ok = e < end;                  // tail mask
        const int  pl = list[e];                  // e < start+CAP guaranteed
        int d = (pl & 0x7fffffff) >> 3;
        d = ok ? d : 0;                           // clamp: unwritten slots are 0xAA poison
        const float s = ok ? ((pl < 0) ? -1.f : 1.f) : 0.f;
        const ushort4 h = *(const ushort4*)(xT + (size_t)d * 32 + bsub * 4);
        a0 += s * __half2float(__ushort_as_half(h.x));
        a1 += s * __half2float(__ushort_as_half(h.y));
        a2 += s * __half2float(__ushort_as_half(h.z));
        a3 += s * __half2float(__ushort_as_half(h.w));
    }
    // reduce across the 8 entry-groups (bits 3..5 of lane)
    #pragma unroll
    for (int m = 8; m <= 32; m <<= 1) {
        a0 += __shfl_xor(a0, m, 64);
        a1 += __shfl_xor(a1, m, 64);
        a2 += __shfl_xor(a2, m, 64);
        a3 += __shfl_xor(a3, m, 64);
    }
    if (lane < 8) {
        red[w][bsub * 4 + 0] = a0;
        red[w][bsub * 4 + 1] = a1;
        red[w][bsub * 4 + 2] = a2;
        red[w][bsub * 4 + 3] = a3;
    }
    __syncthreads();
    if (tid < 64) {
        const int which = tid >> 5;               // 0/1: bucket within block
        const int b     = tid & 31;
        const int pb    = blockIdx.x * 2 + which;
        const float v   = red[which * 2][b] + red[which * 2 + 1][b];
        out[(size_t)b * PROJ + pb] = v * SCALE;   // every (b,p) written exactly once
    }
}

// ---------------- fallback (R1 kernel) if ws too small ----------------
#define BG 8
#define NCHUNK 64
#define BLOCK 1024
__global__ __launch_bounds__(BLOCK, 4)
void sjlt_scatter_fallback(const float* __restrict__ x,
                           const int* __restrict__ idx,
                           const int* __restrict__ sgn,
                           float* __restrict__ out) {
    __shared__ float acc[BG * PROJ];
    const int tid = threadIdx.x;
    #pragma unroll
    for (int i = 0; i < (BG * PROJ) / BLOCK; ++i) acc[i * BLOCK + tid] = 0.0f;
    __syncthreads();
    const int chunk = D_TOTAL / NCHUNK;
    const int d0 = blockIdx.x * chunk;
    const int d1 = d0 + chunk;
    const int bg = blockIdx.y * BG;
    for (int d = d0 + tid; d < d1; d += BLOCK) {
        const int4 i0 = *(const int4*)(idx + (size_t)d * C_SK);
        const int4 i1 = *(const int4*)(idx + (size_t)d * C_SK + 4);
        const int4 s0 = *(const int4*)(sgn + (size_t)d * C_SK);
        const int4 s1 = *(const int4*)(sgn + (size_t)d * C_SK + 4);
        #pragma unroll
        for (int b = 0; b < BG; ++b) {
            const float xv = __builtin_nontemporal_load(x + (size_t)(bg + b) * D_TOTAL + d);
            const unsigned xb = __float_as_uint(xv);
            float* accb = acc + b * PROJ;
            atomicAdd(accb + i0.x, __uint_as_float(xb ^ ((unsigned)s0.x & 0x80000000u)));
            atomicAdd(accb + i0.y, __uint_as_float(xb ^ ((unsigned)s0.y & 0x80000000u)));
            atomicAdd(accb + i0.z, __uint_as_float(xb ^ ((unsigned)s0.z & 0x80000000u)));
            atomicAdd(accb + i0.w, __uint_as_float(xb ^ ((unsigned)s0.w & 0x80000000u)));
            atomicAdd(accb + i1.x, __uint_as_float(xb ^ ((unsigned)s1.x & 0x80000000u)));
            atomicAdd(accb + i1.y, __uint_as_float(xb ^ ((unsigned)s1.y & 0x80000000u)));
            atomicAdd(accb + i1.z, __uint_as_float(xb ^ ((unsigned)s1.z & 0x80000000u)));
            atomicAdd(accb + i1.w, __uint_as_float(xb ^ ((unsigned)s1.w & 0x80000000u)));
        }
    }
    __syncthreads();
    #pragma unroll
    for (int i = 0; i < (BG * PROJ) / BLOCK; ++i) {
        const int lin = i * BLOCK + tid;
        const int b = lin >> 12;
        const int pp = lin & (PROJ - 1);
        unsafeAtomicAdd(out + (size_t)(bg + b) * PROJ + pp, acc[lin] * SCALE);
    }
}

extern "C" void kernel_launch(void* const* d_in, const int* in_sizes, int n_in,
                              void* d_out, int out_size, void* d_ws, size_t ws_size,
                              hipStream_t stream) {
    const float* x   = (const float*)d_in[0];
    const int*   idx = (const int*)d_in[1];
    const int*   sgn = (const int*)d_in[2];
    float*       out = (float*)d_out;

    if (ws_size < WS_NEEDED) {
        // not enough scratch: R1 LDS-atomic path
        hipMemsetAsync(out, 0, (size_t)out_size * sizeof(float), stream);
        dim3 grid(NCHUNK, 32 / BG);
        sjlt_scatter_fallback<<<grid, BLOCK, 0, stream>>>(x, idx, sgn, out);
        return;
    }

    char* ws = (char*)d_ws;
    int*            cursors = (int*)(ws);
    int*            list    = (int*)(ws + LIST_OFF);
    unsigned short* xT      = (unsigned short*)(ws + XT_OFF);

    init_cursors_kernel<<<16, 256, 0, stream>>>(cursors);
    scatter_sort_kernel<<<2048, 256, 0, stream>>>(idx, sgn, cursors, list);
    transpose_kernel<<<977, 1024, 0, stream>>>(x, xT);
    gather_kernel<<<PROJ / 2, 256, 0, stream>>>(cursors, list, xT, out);
    // out is fully overwritten by gather_kernel -> no memset needed
}

// Round 3
// 478.372 us; speedup vs baseline: 3.0370x; 1.8400x over previous
//
#include <hip/hip_runtime.h>
#include <hip/hip_fp16.h>

// SJLT projection: out[b, idx[d,j]] += x[b,d]*sgn[d,j]; out *= 1/sqrt(8)
// B=32, D=1e6, P=4096, c=8.
//
// R2 post-mortem: single-pass scatter sort = 539 us, WRITE_SIZE 421 MB
// (13x amplification from random 4B stores) + 8M global atomics.
// R3: two-level LDS-staged multisplit:
//   K0: init cursors
//   KA: 8M entries -> 64 coarse partitions (bucket>>6), LDS-staged, coalesced
//   KB: each partition -> 64 fine buckets (bucket&63) -> gather list
//   K4: transpose x -> x_T[1e6][32] fp16 (overlays dead listA region)
//   K5: gather per bucket, register accumulation, zero hot-phase atomics

#define D_TOTAL 1000000
#define PROJ    4096
#define C_SK    8
#define NE      (D_TOTAL * C_SK)     // 8,000,000 entries
#define SCALE   0.35355339059327373f

#define CAPA    131072               // per coarse-partition capacity (mu+17sig)
#define CAP     2304                 // per fine-bucket capacity (mu+7.9sig)
#define BINCAP  112                  // per-tile per-bin LDS cap (mu=64, +6sig)

// ws layout
#define CURA_OFF   0                 // 64 ints
#define CURB_OFF   16384             // 4096 ints
#define LISTB_OFF  65536
#define LISTB_SZ   ((size_t)PROJ * CAP * 4)            // 37,748,736
#define SHARED_OFF (LISTB_OFF + LISTB_SZ)              // 37,814,272
#define LISTA_SZ   ((size_t)64 * CAPA * 8)             // 67,108,864
#define XT_SZ      ((size_t)D_TOTAL * 32 * 2)          // 64,000,000 (< LISTA_SZ)
#define WS_NEEDED  (SHARED_OFF + LISTA_SZ)             // 104,923,136

// ---------------- K0: init cursors ----------------
__global__ void init_cursors_kernel(int* __restrict__ curA, int* __restrict__ curB) {
    int i = blockIdx.x * blockDim.x + threadIdx.x;
    if (i < 64)   curA[i] = i * CAPA;
    if (i < PROJ) curB[i] = i * CAP;
}

// ---------------- KA: coarse split (64 partitions) ----------------
// grid 1954 x 256; tile = 4096 entries; entry payload int2 {sign|g, bucket}
__global__ __launch_bounds__(256, 2)
void pass_a_kernel(const int* __restrict__ idx, const int* __restrict__ sgn,
                   int* __restrict__ curA, int2* __restrict__ listA) {
    __shared__ int2 stage[64 * BINCAP];      // 57,344 B
    __shared__ int  cnt[64];
    __shared__ int  basek[64];
    const int tid = threadIdx.x;
    if (tid < 64) cnt[tid] = 0;
    __syncthreads();

    const int v0 = blockIdx.x * 1024;        // int4 index base (tile/4)
    #pragma unroll
    for (int k = 0; k < 4; ++k) {
        const int vi = v0 + k * 256 + tid;
        if (vi < NE / 4) {
            const int4 i4 = ((const int4*)idx)[vi];
            const int4 s4 = ((const int4*)sgn)[vi];
            const int  g0 = vi * 4;
            #pragma unroll
            for (int m = 0; m < 4; ++m) {
                const int bucket = (m == 0) ? i4.x : (m == 1) ? i4.y : (m == 2) ? i4.z : i4.w;
                const int sg     = (m == 0) ? s4.x : (m == 1) ? s4.y : (m == 2) ? s4.z : s4.w;
                const int kb  = bucket >> 6;
                int2 e;
                e.x = (g0 + m) | (int)((unsigned)sg & 0x80000000u);
                e.y = bucket;
                const int r = atomicAdd(&cnt[kb], 1);
                if (r < BINCAP) {
                    stage[kb * BINCAP + r] = e;
                } else {                      // rare slow path (correctness net)
                    const int pos = atomicAdd(&curA[kb], 1);
                    if (pos < (kb + 1) * CAPA) listA[pos] = e;
                }
            }
        }
    }
    __syncthreads();
    if (tid < 64) {
        const int m = min(cnt[tid], BINCAP);
        basek[tid] = atomicAdd(&curA[tid], m);
        cnt[tid]   = m;
    }
    __syncthreads();
    for (int kb = 0; kb < 64; ++kb) {
        const int m = cnt[kb];
        const int base = basek[kb];
        const int lim  = (kb + 1) * CAPA;
        for (int i = tid; i < m; i += 256)
            if (base + i < lim) listA[base + i] = stage[kb * BINCAP + i];
    }
}

// ---------------- KB: fine split (64 buckets within each partition) ----------------
// grid 2048 = 64 parts x 32 tiles of 4096
__global__ __launch_bounds__(256, 4)
void pass_b_kernel(const int* __restrict__ curA, const int2* __restrict__ listA,
                   int* __restrict__ curB, int* __restrict__ listB) {
    __shared__ int stage[64 * BINCAP];       // 28,672 B
    __shared__ int cnt[64];
    __shared__ int basek[64];
    const int tid  = threadIdx.x;
    const int part = blockIdx.x >> 5;
    const int tile = blockIdx.x & 31;
    if (tid < 64) cnt[tid] = 0;
    __syncthreads();

    const int pstart = part * CAPA;
    const int pcount = min(curA[part] - pstart, CAPA);
    const int t0 = tile * 4096;
    const int t1 = min(t0 + 4096, pcount);

    for (int i = t0 + tid; i < t1; i += 256) {
        const int2 e = listA[pstart + i];
        const int  kb = e.y & 63;
        const int  r  = atomicAdd(&cnt[kb], 1);
        if (r < BINCAP) {
            stage[kb * BINCAP + r] = e.x;
        } else {
            const int pf  = part * 64 + kb;
            const int pos = atomicAdd(&curB[pf], 1);
            if (pos < (pf + 1) * CAP) listB[pos] = e.x;
        }
    }
    __syncthreads();
    if (tid < 64) {
        const int m = min(cnt[tid], BINCAP);
        basek[tid] = atomicAdd(&curB[part * 64 + tid], m);
        cnt[tid]   = m;
    }
    __syncthreads();
    for (int kb = 0; kb < 64; ++kb) {
        const int m = cnt[kb];
        const int base = basek[kb];
        const int lim  = (part * 64 + kb + 1) * CAP;
        for (int i = tid; i < m; i += 256)
            if (base + i < lim) listB[base + i] = stage[kb * BINCAP + i];
    }
}

// ---------------- K4: transpose x[32][1e6] -> x_T[1e6][32] fp16 ----------------
__global__ __launch_bounds__(1024)
void transpose_kernel(const float* __restrict__ x, unsigned short* __restrict__ xT) {
    __shared__ float tile[32][1025];
    const int tid = threadIdx.x;
    const int d0 = blockIdx.x * 1024;

    if (d0 + 1024 <= D_TOTAL) {
        #pragma unroll
        for (int rr = 0; rr < 8; ++rr) {
            const int r = rr * 4 + (tid >> 8);
            const int c = (tid & 255) * 4;
            const float4 v = *(const float4*)(x + (size_t)r * D_TOTAL + d0 + c);
            tile[r][c] = v.x; tile[r][c+1] = v.y; tile[r][c+2] = v.z; tile[r][c+3] = v.w;
        }
    } else {
        for (int rr = 0; rr < 8; ++rr) {
            const int r = rr * 4 + (tid >> 8);
            const int c = (tid & 255) * 4;
            for (int m = 0; m < 4; ++m) {
                const int d = d0 + c + m;
                tile[r][c + m] = (d < D_TOTAL) ? x[(size_t)r * D_TOTAL + d] : 0.f;
            }
        }
    }
    __syncthreads();

    #pragma unroll
    for (int k = 0; k < 8; ++k) {
        const int i  = k * 1024 + tid;
        const int dl = i >> 3;
        const int b0 = (i & 7) * 4;
        if (d0 + dl < D_TOTAL) {
            ushort4 h;
            h.x = __half_as_ushort(__float2half(tile[b0    ][dl]));
            h.y = __half_as_ushort(__float2half(tile[b0 + 1][dl]));
            h.z = __half_as_ushort(__float2half(tile[b0 + 2][dl]));
            h.w = __half_as_ushort(__float2half(tile[b0 + 3][dl]));
            *(ushort4*)(xT + (size_t)d0 * 32 + (size_t)i * 4) = h;
        }
    }
}

// ---------------- K5: gather — 1 bucket/block, 4 waves ----------------
__global__ __launch_bounds__(256, 8)
void gather_kernel(const int* __restrict__ curB, const int* __restrict__ listB,
                   const unsigned short* __restrict__ xT, float* __restrict__ out) {
    __shared__ float red[4][32];
    const int tid  = threadIdx.x;
    const int w    = tid >> 6;
    const int lane = tid & 63;
    const int p    = blockIdx.x;
    const int start = p * CAP;
    const int end   = min(curB[p], start + CAP);
    const int g8   = lane >> 3;
    const int bsub = lane & 7;

    float a0 = 0.f, a1 = 0.f, a2 = 0.f, a3 = 0.f;
    #pragma unroll 4
    for (int i0 = start + w * 8; i0 < end; i0 += 32) {
        const int  e  = i0 + g8;
        const bool ok = e < end;
        const int  ec = ok ? e : start;
        const int  pl = listB[ec];
        int d = (pl & 0x7fffffff) >> 3;
        const float s = ok ? ((pl < 0) ? -1.f : 1.f) : 0.f;
        const ushort4 h = *(const ushort4*)(xT + (size_t)d * 32 + bsub * 4);
        a0 += s * __half2float(__ushort_as_half(h.x));
        a1 += s * __half2float(__ushort_as_half(h.y));
        a2 += s * __half2float(__ushort_as_half(h.z));
        a3 += s * __half2float(__ushort_as_half(h.w));
    }
    #pragma unroll
    for (int m = 8; m <= 32; m <<= 1) {
        a0 += __shfl_xor(a0, m, 64);
        a1 += __shfl_xor(a1, m, 64);
        a2 += __shfl_xor(a2, m, 64);
        a3 += __shfl_xor(a3, m, 64);
    }
    if (lane < 8) {
        red[w][bsub * 4 + 0] = a0;
        red[w][bsub * 4 + 1] = a1;
        red[w][bsub * 4 + 2] = a2;
        red[w][bsub * 4 + 3] = a3;
    }
    __syncthreads();
    if (tid < 32) {
        const float v = red[0][tid] + red[1][tid] + red[2][tid] + red[3][tid];
        out[(size_t)tid * PROJ + p] = v * SCALE;
    }
}

// ---------------- fallback (R1 kernel) if ws too small ----------------
#define BG 8
#define NCHUNK 64
#define BLOCK 1024
__global__ __launch_bounds__(BLOCK, 4)
void sjlt_scatter_fallback(const float* __restrict__ x,
                           const int* __restrict__ idx,
                           const int* __restrict__ sgn,
                           float* __restrict__ out) {
    __shared__ float acc[BG * PROJ];
    const int tid = threadIdx.x;
    #pragma unroll
    for (int i = 0; i < (BG * PROJ) / BLOCK; ++i) acc[i * BLOCK + tid] = 0.0f;
    __syncthreads();
    const int chunk = D_TOTAL / NCHUNK;
    const int d0 = blockIdx.x * chunk;
    const int d1 = d0 + chunk;
    const int bg = blockIdx.y * BG;
    for (int d = d0 + tid; d < d1; d += BLOCK) {
        const int4 i0 = *(const int4*)(idx + (size_t)d * C_SK);
        const int4 i1 = *(const int4*)(idx + (size_t)d * C_SK + 4);
        const int4 s0 = *(const int4*)(sgn + (size_t)d * C_SK);
        const int4 s1 = *(const int4*)(sgn + (size_t)d * C_SK + 4);
        #pragma unroll
        for (int b = 0; b < BG; ++b) {
            const float xv = __builtin_nontemporal_load(x + (size_t)(bg + b) * D_TOTAL + d);
            const unsigned xb = __float_as_uint(xv);
            float* accb = acc + b * PROJ;
            atomicAdd(accb + i0.x, __uint_as_float(xb ^ ((unsigned)s0.x & 0x80000000u)));
            atomicAdd(accb + i0.y, __uint_as_float(xb ^ ((unsigned)s0.y & 0x80000000u)));
            atomicAdd(accb + i0.z, __uint_as_float(xb ^ ((unsigned)s0.z & 0x80000000u)));
            atomicAdd(accb + i0.w, __uint_as_float(xb ^ ((unsigned)s0.w & 0x80000000u)));
            atomicAdd(accb + i1.x, __uint_as_float(xb ^ ((unsigned)s1.x & 0x80000000u)));
            atomicAdd(accb + i1.y, __uint_as_float(xb ^ ((unsigned)s1.y & 0x80000000u)));
            atomicAdd(accb + i1.z, __uint_as_float(xb ^ ((unsigned)s1.z & 0x80000000u)));
            atomicAdd(accb + i1.w, __uint_as_float(xb ^ ((unsigned)s1.w & 0x80000000u)));
        }
    }
    __syncthreads();
    #pragma unroll
    for (int i = 0; i < (BG * PROJ) / BLOCK; ++i) {
        const int lin = i * BLOCK + tid;
        const int b = lin >> 12;
        const int pp = lin & (PROJ - 1);
        unsafeAtomicAdd(out + (size_t)(bg + b) * PROJ + pp, acc[lin] * SCALE);
    }
}

extern "C" void kernel_launch(void* const* d_in, const int* in_sizes, int n_in,
                              void* d_out, int out_size, void* d_ws, size_t ws_size,
                              hipStream_t stream) {
    const float* x   = (const float*)d_in[0];
    const int*   idx = (const int*)d_in[1];
    const int*   sgn = (const int*)d_in[2];
    float*       out = (float*)d_out;

    if (ws_size < WS_NEEDED) {
        hipMemsetAsync(out, 0, (size_t)out_size * sizeof(float), stream);
        dim3 grid(NCHUNK, 32 / BG);
        sjlt_scatter_fallback<<<grid, BLOCK, 0, stream>>>(x, idx, sgn, out);
        return;
    }

    char* ws = (char*)d_ws;
    int*            curA  = (int*)(ws + CURA_OFF);
    int*            curB  = (int*)(ws + CURB_OFF);
    int*            listB = (int*)(ws + LISTB_OFF);
    int2*           listA = (int2*)(ws + SHARED_OFF);
    unsigned short* xT    = (unsigned short*)(ws + SHARED_OFF);  // overlays listA

    init_cursors_kernel<<<(PROJ + 255) / 256, 256, 0, stream>>>(curA, curB);
    pass_a_kernel<<<(NE / 4 + 1023) / 1024, 256, 0, stream>>>(idx, sgn, curA, listA);
    pass_b_kernel<<<64 * 32, 256, 0, stream>>>(curA, listA, curB, listB);
    transpose_kernel<<<977, 1024, 0, stream>>>(x, xT);       // after KB: xT kills listA
    gather_kernel<<<PROJ, 256, 0, stream>>>(curB, listB, xT, out);
    // out fully overwritten by gather -> no memset needed
}

// Round 4
// 458.596 us; speedup vs baseline: 3.1679x; 1.0431x over previous
//
#include <hip/hip_runtime.h>
#include <hip/hip_fp16.h>

// SJLT projection: out[b, idx[d,j]] += x[b,d]*sgn[d,j]; out *= 1/sqrt(8)
// B=32, D=1e6, P=4096, c=8.
//
// R3 post-mortem: gather = 149 us (algorithmic 8M x 64B random-line cost,
// ~3.35 TB/s effective). Prep passes = ~330 us vs ~35 us streaming floor:
// per-lane LDS rank atomics (3.1 cyc/lane measured in R1), 8B payloads,
// serial flush, low occupancy.
// R4: ballot-based peer ranking (leader-only LDS atomics), 4B packed
// payloads {sign:31, fine6:24..29, g:0..22}, 8192-entry tiles at 3 blocks/CU,
// wave-parallel flush, 4-blocks/CU transpose, gather with 16 slots x 4 lanes
// x 16B loads.

#define D_TOTAL 1000000
#define PROJ    4096
#define C_SK    8
#define NE      (D_TOTAL * C_SK)     // 8,000,000 entries
#define SCALE   0.35355339059327373f

#define CAPA    131072               // per coarse-partition cap (mu+17sig)
#define CAP     2304                 // per fine-bucket cap (mu+7.9sig)
#define BINCAP  192                  // per-tile per-bin LDS cap (mu=128,+5.7sig)
#define TILE    8192                 // entries per block in split passes

// ws layout
#define CURA_OFF   0                 // 64 ints
#define CURB_OFF   16384             // 4096 ints
#define LISTB_OFF  65536
#define LISTB_SZ   ((size_t)PROJ * CAP * 4)            // 37,748,736
#define SHARED_OFF (LISTB_OFF + LISTB_SZ)              // 37,814,272
#define LISTA_SZ   ((size_t)64 * CAPA * 4)             // 33,554,432
#define XT_SZ      ((size_t)D_TOTAL * 32 * 2)          // 64,000,000
#define WS_NEEDED  (SHARED_OFF + XT_SZ)                // 101,814,272 (xT overlays listA)

// ---------------- K0: init cursors ----------------
__global__ void init_cursors_kernel(int* __restrict__ curA, int* __restrict__ curB) {
    int i = blockIdx.x * blockDim.x + threadIdx.x;
    if (i < 64)   curA[i] = i * CAPA;
    if (i < PROJ) curB[i] = i * CAP;
}

// Ballot-based multisplit rank+stage. All 64 lanes of the wave MUST reach
// this call (no divergent skip); `ok` masks tail lanes. kb in [0,64).
__device__ __forceinline__ void rank_and_stage(bool ok, int kb, int payload,
                                               int* __restrict__ cnt,
                                               int* __restrict__ stage,
                                               int* __restrict__ gcur,
                                               int* __restrict__ glist,
                                               int gcur_idx, int glim) {
    const unsigned long long valid = __ballot(ok);
    unsigned long long mask = valid;
    #pragma unroll
    for (int b = 0; b < 6; ++b) {
        const unsigned long long vote = __ballot((kb >> b) & 1);
        mask &= ((kb >> b) & 1) ? vote : ~vote;
    }
    if (ok) {
        const int lane = threadIdx.x & 63;
        const int rank = __popcll(mask & ((1ULL << lane) - 1ULL));
        const int leader = __ffsll((unsigned long long)mask) - 1;
        int base = 0;
        if (rank == 0) base = atomicAdd(&cnt[kb], __popcll(mask));
        base = __shfl(base, leader, 64);
        const int pos = base + rank;
        if (pos < BINCAP) {
            stage[kb * BINCAP + pos] = payload;
        } else {                       // rare overflow: direct global placement
            const int gp = atomicAdd(&gcur[gcur_idx], 1);
            if (gp < glim) glist[gp] = payload;
        }
    }
}

// shared flush: reserve global space per bin, copy wave-parallel (16 bins/wave)
__device__ __forceinline__ void flush_bins(int* __restrict__ cnt,
                                           int* __restrict__ basek,
                                           const int* __restrict__ stage,
                                           int* __restrict__ gcur,
                                           int* __restrict__ glist,
                                           int gidx0, int capPer) {
    const int tid = threadIdx.x;
    if (tid < 64) {
        const int m = min(cnt[tid], BINCAP);
        cnt[tid]   = m;
        basek[tid] = atomicAdd(&gcur[gidx0 + tid], m);
    }
    __syncthreads();
    const int w = tid >> 6, lane = tid & 63;
    #pragma unroll 1
    for (int bi = 0; bi < 16; ++bi) {
        const int kb  = w * 16 + bi;
        const int m   = cnt[kb];
        const int gb  = basek[kb];
        const int lim = (gidx0 + kb + 1) * capPer;
        for (int i = lane; i < m; i += 64)
            if (gb + i < lim) glist[gb + i] = stage[kb * BINCAP + i];
    }
}

// ---------------- KA: coarse split (bucket>>6) ----------------
// grid 977 x 256; tile = 8192 entries; payload {sign:31, low6:24..29, g:0..22}
__global__ __launch_bounds__(256, 3)
void pass_a_kernel(const int* __restrict__ idx, const int* __restrict__ sgn,
                   int* __restrict__ curA, int* __restrict__ listA) {
    __shared__ int stage[64 * BINCAP];       // 49,152 B
    __shared__ int cnt[64];
    __shared__ int basek[64];
    const int tid = threadIdx.x;
    if (tid < 64) cnt[tid] = 0;
    __syncthreads();

    const int v0 = blockIdx.x * (TILE / 4);  // int4 base
    #pragma unroll 1
    for (int k = 0; k < 8; ++k) {
        const int vi = v0 + k * 256 + tid;
        const bool okv = vi < NE / 4;
        int4 i4 = {0,0,0,0}, s4 = {0,0,0,0};
        if (okv) { i4 = ((const int4*)idx)[vi]; s4 = ((const int4*)sgn)[vi]; }
        const int g0 = vi * 4;
        #pragma unroll
        for (int m = 0; m < 4; ++m) {
            const int bucket = (m == 0) ? i4.x : (m == 1) ? i4.y : (m == 2) ? i4.z : i4.w;
            const int sg     = (m == 0) ? s4.x : (m == 1) ? s4.y : (m == 2) ? s4.z : s4.w;
            const int kb = okv ? (bucket >> 6) : 0;
            const int payload = (g0 + m) | ((bucket & 63) << 24)
                              | (int)((unsigned)sg & 0x80000000u);
            rank_and_stage(okv, kb, payload, cnt, stage, curA, listA, kb, (kb + 1) * CAPA);
        }
    }
    __syncthreads();
    flush_bins(cnt, basek, stage, curA, listA, 0, CAPA);
}

// ---------------- KB: fine split (bucket&63) within each partition ----------------
// grid 1024 = 64 parts x 16 tiles of 8192
__global__ __launch_bounds__(256, 3)
void pass_b_kernel(const int* __restrict__ curA, const int* __restrict__ listA,
                   int* __restrict__ curB, int* __restrict__ listB) {
    __shared__ int stage[64 * BINCAP];
    __shared__ int cnt[64];
    __shared__ int basek[64];
    const int tid  = threadIdx.x;
    const int part = blockIdx.x >> 4;
    const int tile = blockIdx.x & 15;
    if (tid < 64) cnt[tid] = 0;
    __syncthreads();

    const int pstart = part * CAPA;
    const int pcount = min(curA[part] - pstart, CAPA);
    const int t0 = tile * TILE;
    const int t1 = min(t0 + TILE, pcount);

    #pragma unroll 1
    for (int k = 0; k < TILE / 256; ++k) {
        const int i  = t0 + k * 256 + tid;
        const bool ok = i < t1;
        const int e  = ok ? listA[pstart + i] : 0;
        const int kb = (e >> 24) & 63;
        const int payload = e & 0x807FFFFF;          // keep sign + g
        rank_and_stage(ok, kb, payload, cnt, stage, curB, listB,
                       part * 64 + kb, (part * 64 + kb + 1) * CAP);
    }
    __syncthreads();
    flush_bins(cnt, basek, stage, curB, listB, part * 64, CAP);
}

// ---------------- K4: transpose x[32][1e6] -> x_T[1e6][32] fp16 ----------------
// block 256, d-tile 256, LDS 33 KB -> 4 blocks/CU
__global__ __launch_bounds__(256, 4)
void transpose_kernel(const float* __restrict__ x, unsigned short* __restrict__ xT) {
    __shared__ float tile[32][257];
    const int tid = threadIdx.x;
    const int d0  = blockIdx.x * 256;
    const int row = tid >> 3;                 // 32 rows x 8 threads
    const int c8  = tid & 7;

    if (d0 + 256 <= D_TOTAL) {
        #pragma unroll
        for (int k = 0; k < 8; ++k) {
            const int c = (c8 + 8 * k) * 4;
            const float4 v = *(const float4*)(x + (size_t)row * D_TOTAL + d0 + c);
            tile[row][c] = v.x; tile[row][c+1] = v.y;
            tile[row][c+2] = v.z; tile[row][c+3] = v.w;
        }
    } else {
        for (int k = 0; k < 8; ++k) {
            const int c = (c8 + 8 * k) * 4;
            for (int m = 0; m < 4; ++m) {
                const int d = d0 + c + m;
                tile[row][c + m] = (d < D_TOTAL) ? x[(size_t)row * D_TOTAL + d] : 0.f;
            }
        }
    }
    __syncthreads();

    const int part = tid & 3;                 // batch octet
    #pragma unroll
    for (int k = 0; k < 4; ++k) {
        const int dl = k * 64 + (tid >> 2);
        if (d0 + dl < D_TOTAL) {
            unsigned short h[8];
            #pragma unroll
            for (int i = 0; i < 8; ++i)
                h[i] = __half_as_ushort(__float2half(tile[part * 8 + i][dl]));
            *(uint4*)(xT + ((size_t)(d0 + dl)) * 32 + part * 8) = *(const uint4*)h;
        }
    }
}

// ---------------- K5: gather — 1 bucket/block, 16 slots x 4 lanes x 16B ----------------
__global__ __launch_bounds__(256, 8)
void gather_kernel(const int* __restrict__ curB, const int* __restrict__ listB,
                   const unsigned short* __restrict__ xT, float* __restrict__ out) {
    __shared__ float red[4][32];
    const int tid  = threadIdx.x;
    const int w    = tid >> 6;
    const int lane = tid & 63;
    const int p    = blockIdx.x;
    const int start = p * CAP;
    const int end   = min(curB[p], start + CAP);
    const int slot = lane >> 2;               // 16 entry slots
    const int bq   = lane & 3;                // batch octet (8 b-values, 16B)

    float a0=0.f,a1=0.f,a2=0.f,a3=0.f,a4=0.f,a5=0.f,a6=0.f,a7=0.f;
    #pragma unroll 2
    for (int i0 = start + w * 16; i0 < end; i0 += 64) {
        const int  e  = i0 + slot;
        const bool ok = e < end;
        const int  pl = __builtin_nontemporal_load(listB + (ok ? e : start));
        const int  d  = ok ? ((pl & 0x7FFFFF) >> 3) : 0;
        const float s = ok ? ((pl < 0) ? -1.f : 1.f) : 0.f;
        const uint4 hv = *(const uint4*)(xT + (size_t)d * 32 + bq * 8);
        float2 f;
        f = __half22float2(*(const __half2*)&hv.x); a0 = fmaf(s, f.x, a0); a1 = fmaf(s, f.y, a1);
        f = __half22float2(*(const __half2*)&hv.y); a2 = fmaf(s, f.x, a2); a3 = fmaf(s, f.y, a3);
        f = __half22float2(*(const __half2*)&hv.z); a4 = fmaf(s, f.x, a4); a5 = fmaf(s, f.y, a5);
        f = __half22float2(*(const __half2*)&hv.w); a6 = fmaf(s, f.x, a6); a7 = fmaf(s, f.y, a7);
    }
    // reduce across the 16 slots (lane bits 2..5)
    #pragma unroll
    for (int m = 4; m <= 32; m <<= 1) {
        a0 += __shfl_xor(a0, m, 64); a1 += __shfl_xor(a1, m, 64);
        a2 += __shfl_xor(a2, m, 64); a3 += __shfl_xor(a3, m, 64);
        a4 += __shfl_xor(a4, m, 64); a5 += __shfl_xor(a5, m, 64);
        a6 += __shfl_xor(a6, m, 64); a7 += __shfl_xor(a7, m, 64);
    }
    if (lane < 4) {
        float* r = &red[w][lane * 8];
        r[0]=a0; r[1]=a1; r[2]=a2; r[3]=a3; r[4]=a4; r[5]=a5; r[6]=a6; r[7]=a7;
    }
    __syncthreads();
    if (tid < 32) {
        const float v = red[0][tid] + red[1][tid] + red[2][tid] + red[3][tid];
        out[(size_t)tid * PROJ + p] = v * SCALE;
    }
}

// ---------------- fallback (R1 kernel) if ws too small ----------------
#define BG 8
#define NCHUNK 64
#define BLOCK 1024
__global__ __launch_bounds__(BLOCK, 4)
void sjlt_scatter_fallback(const float* __restrict__ x,
                           const int* __restrict__ idx,
                           const int* __restrict__ sgn,
                           float* __restrict__ out) {
    __shared__ float acc[BG * PROJ];
    const int tid = threadIdx.x;
    #pragma unroll
    for (int i = 0; i < (BG * PROJ) / BLOCK; ++i) acc[i * BLOCK + tid] = 0.0f;
    __syncthreads();
    const int chunk = D_TOTAL / NCHUNK;
    const int d0 = blockIdx.x * chunk;
    const int d1 = d0 + chunk;
    const int bg = blockIdx.y * BG;
    for (int d = d0 + tid; d < d1; d += BLOCK) {
        const int4 i0 = *(const int4*)(idx + (size_t)d * C_SK);
        const int4 i1 = *(const int4*)(idx + (size_t)d * C_SK + 4);
        const int4 s0 = *(const int4*)(sgn + (size_t)d * C_SK);
        const int4 s1 = *(const int4*)(sgn + (size_t)d * C_SK + 4);
        #pragma unroll
        for (int b = 0; b < BG; ++b) {
            const float xv = __builtin_nontemporal_load(x + (size_t)(bg + b) * D_TOTAL + d);
            const unsigned xb = __float_as_uint(xv);
            float* accb = acc + b * PROJ;
            atomicAdd(accb + i0.x, __uint_as_float(xb ^ ((unsigned)s0.x & 0x80000000u)));
            atomicAdd(accb + i0.y, __uint_as_float(xb ^ ((unsigned)s0.y & 0x80000000u)));
            atomicAdd(accb + i0.z, __uint_as_float(xb ^ ((unsigned)s0.z & 0x80000000u)));
            atomicAdd(accb + i0.w, __uint_as_float(xb ^ ((unsigned)s0.w & 0x80000000u)));
            atomicAdd(accb + i1.x, __uint_as_float(xb ^ ((unsigned)s1.x & 0x80000000u)));
            atomicAdd(accb + i1.y, __uint_as_float(xb ^ ((unsigned)s1.y & 0x80000000u)));
            atomicAdd(accb + i1.z, __uint_as_float(xb ^ ((unsigned)s1.z & 0x80000000u)));
            atomicAdd(accb + i1.w, __uint_as_float(xb ^ ((unsigned)s1.w & 0x80000000u)));
        }
    }
    __syncthreads();
    #pragma unroll
    for (int i = 0; i < (BG * PROJ) / BLOCK; ++i) {
        const int lin = i * BLOCK + tid;
        const int b = lin >> 12;
        const int pp = lin & (PROJ - 1);
        unsafeAtomicAdd(out + (size_t)(bg + b) * PROJ + pp, acc[lin] * SCALE);
    }
}

extern "C" void kernel_launch(void* const* d_in, const int* in_sizes, int n_in,
                              void* d_out, int out_size, void* d_ws, size_t ws_size,
                              hipStream_t stream) {
    const float* x   = (const float*)d_in[0];
    const int*   idx = (const int*)d_in[1];
    const int*   sgn = (const int*)d_in[2];
    float*       out = (float*)d_out;

    if (ws_size < WS_NEEDED) {
        hipMemsetAsync(out, 0, (size_t)out_size * sizeof(float), stream);
        dim3 grid(NCHUNK, 32 / BG);
        sjlt_scatter_fallback<<<grid, BLOCK, 0, stream>>>(x, idx, sgn, out);
        return;
    }

    char* ws = (char*)d_ws;
    int*            curA  = (int*)(ws + CURA_OFF);
    int*            curB  = (int*)(ws + CURB_OFF);
    int*            listB = (int*)(ws + LISTB_OFF);
    int*            listA = (int*)(ws + SHARED_OFF);
    unsigned short* xT    = (unsigned short*)(ws + SHARED_OFF);  // overlays listA

    init_cursors_kernel<<<(PROJ + 255) / 256, 256, 0, stream>>>(curA, curB);
    pass_a_kernel<<<(NE / 4 + (TILE/4) - 1) / (TILE/4), 256, 0, stream>>>(idx, sgn, curA, listA);
    pass_b_kernel<<<64 * 16, 256, 0, stream>>>(curA, listA, curB, listB);
    transpose_kernel<<<(D_TOTAL + 255) / 256, 256, 0, stream>>>(x, xT);  // clobbers listA (dead)
    gather_kernel<<<PROJ, 256, 0, stream>>>(curB, listB, xT, out);
    // out fully overwritten by gather -> no memset needed
}